// Round 12
// baseline (273.060 us; speedup 1.0000x reference)
//
#include <hip/hip_runtime.h>

#define N_NODES 100000
#define N_EDGES 1000000
#define IN_CH 128
#define HID_CH 64
#define N_CLS 40

#define NODE_CAP 40            // per-node srow capacity (mean deg 10; P(deg>=40) ~ 7e-13)
#define SCATG 1024             // scatter grid: 4 blocks/CU, each thread owns 4 edges
#define NBUCK 782              // fallback bucket scheme
#define BCAP 1664
#define NCOUNT 256

static inline int cdiv(int a, int b) { return (a + b - 1) / b; }

using bf16x8 = __attribute__((ext_vector_type(8))) short;   // 8 bf16 (4 VGPRs)
using f32x4  = __attribute__((ext_vector_type(4))) float;   // MFMA accumulator

// RNE float->bf16 pack (a in low 16, b in high 16)
__device__ __forceinline__ unsigned pack_bf2(float a, float b) {
    unsigned ua = __float_as_uint(a), ub = __float_as_uint(b);
    ua += 0x7fffu + ((ua >> 16) & 1u);
    ub += 0x7fffu + ((ub >> 16) & 1u);
    return (ua >> 16) | (ub & 0xffff0000u);
}
__device__ __forceinline__ unsigned short bf16_of(float a) {
    unsigned ua = __float_as_uint(a);
    ua += 0x7fffu + ((ua >> 16) & 1u);
    return (unsigned short)(ua >> 16);
}
__device__ __forceinline__ float bf_lo(unsigned u) { return __uint_as_float(u << 16); }
__device__ __forceinline__ float bf_hi(unsigned u) { return __uint_as_float(u & 0xffff0000u); }
__device__ __forceinline__ float dinv_of(int d) { return d ? rsqrtf((float)d) : 0.f; }

// ---------------- device helper: one-time wconv work item ----------------
// wtgA [128][128]: c<64 -> w1_init col c ; c>=64 -> w1_root col c-64   (K=128)
// wtgB [80][64]:   c<40 -> w2_init col c ; c>=40 -> w2_root col c-40   (K=64)

__device__ __forceinline__ void wconv_item(int id,
                                           const float* __restrict__ w1i, const float* __restrict__ w1r,
                                           const float* __restrict__ w2i, const float* __restrict__ w2r,
                                           unsigned* __restrict__ wtgA, unsigned* __restrict__ wtgB) {
    if (id < 128 * 64) {                    // wtgA: 128 cols x 64 k-pairs
        int c = id >> 6, kp = id & 63;
        int k = kp * 2;
        const float* W = (c < 64) ? w1i : w1r;
        int cc = (c < 64) ? c : c - 64;
        float a = W[(size_t)k * 64 + cc];
        float b = W[(size_t)(k + 1) * 64 + cc];
        wtgA[c * 64 + kp] = pack_bf2(a, b);
    } else if (id < 128 * 64 + 80 * 32) {   // wtgB: 80 cols x 32 k-pairs
        int j = id - 128 * 64;
        int c = j >> 5, kp = j & 31;
        int k = kp * 2;
        const float* W = (c < 40) ? w2i : w2r;
        int cc = (c < 40) ? c : c - 40;
        float a = W[(size_t)k * 40 + cc];
        float b = W[(size_t)(k + 1) * 40 + cc];
        wtgB[c * 32 + kp] = pack_bf2(a, b);
    }
}

// ---------------- DIRECT per-node scatter (tier A): flat 4-edges/thread ----------------
// R11 lesson: the scatter logic is right but was launched at 1 block/CU with
// serial dependent atomic chains -> 9% occupancy, 54us (Little's law). Fix is
// launch shape only: each thread owns 4 consecutive edges (int4 load of
// cols/rows, 4 independent atomic+store pairs), grid 1024 -> 4 blocks/CU,
// 16 waves/CU, 4x explicit MLP. Atomic semantics identical to R11-verified.

__global__ __launch_bounds__(256)
void scatter_direct_wconv_kernel(const int* __restrict__ rows, const int* __restrict__ cols,
                                 int* __restrict__ deg, int* __restrict__ srow, int E,
                                 const float* __restrict__ w1i, const float* __restrict__ w1r,
                                 const float* __restrict__ w2i, const float* __restrict__ w2r,
                                 unsigned* __restrict__ wtgA, unsigned* __restrict__ wtgB) {
    if (blockIdx.x >= SCATG) {             // wconv part (block-uniform branch)
        if (wtgA == nullptr) return;
        wconv_item((blockIdx.x - SCATG) * 256 + threadIdx.x, w1i, w1r, w2i, w2r, wtgA, wtgB);
        return;
    }
    const int j0 = (blockIdx.x * 256 + threadIdx.x) * 4;
    if (j0 + 3 < E) {
        int4 c4 = *reinterpret_cast<const int4*>(&cols[j0]);
        int4 r4 = *reinterpret_cast<const int4*>(&rows[j0]);
        int s0 = atomicAdd(&deg[c4.x], 1);
        int s1 = atomicAdd(&deg[c4.y], 1);
        int s2 = atomicAdd(&deg[c4.z], 1);
        int s3 = atomicAdd(&deg[c4.w], 1);
        if (s0 < NODE_CAP) srow[c4.x * NODE_CAP + s0] = r4.x;
        if (s1 < NODE_CAP) srow[c4.y * NODE_CAP + s1] = r4.y;
        if (s2 < NODE_CAP) srow[c4.z * NODE_CAP + s2] = r4.z;
        if (s3 < NODE_CAP) srow[c4.w * NODE_CAP + s3] = r4.w;
    } else {
#pragma unroll
        for (int u = 0; u < 4; ++u) {
            int j = j0 + u;
            if (j < E) {
                int c = cols[j];
                int slot = atomicAdd(&deg[c], 1);
                if (slot < NODE_CAP)
                    srow[c * NODE_CAP + slot] = rows[j];
            }
        }
    }
}

// ---------------- fallback prep (R10-verified padded-bucket scheme) ----------------

__global__ __launch_bounds__(256)
void bucket_scatter_wconv_kernel(const int* __restrict__ rows, const int* __restrict__ cols,
                                 int* __restrict__ gcursor, int* __restrict__ pedge, int E,
                                 const float* __restrict__ w1i, const float* __restrict__ w1r,
                                 const float* __restrict__ w2i, const float* __restrict__ w2r,
                                 unsigned* __restrict__ wtgA, unsigned* __restrict__ wtgB) {
    if (blockIdx.x >= NCOUNT) {
        if (wtgA == nullptr) return;
        wconv_item((blockIdx.x - NCOUNT) * 256 + threadIdx.x, w1i, w1r, w2i, w2r, wtgA, wtgB);
        return;
    }
    __shared__ int cur[NBUCK];
    for (int i = threadIdx.x; i < NBUCK; i += 256) cur[i] = 0;
    __syncthreads();
    int per = (E + NCOUNT - 1) / NCOUNT;
    int s = blockIdx.x * per;
    int e = min(E, s + per);
    for (int j = s + threadIdx.x; j < e; j += 256)
        atomicAdd(&cur[cols[j] >> 7], 1);
    __syncthreads();
    for (int i = threadIdx.x; i < NBUCK; i += 256) {
        int h = cur[i];
        cur[i] = h ? (i * BCAP + atomicAdd(&gcursor[i], h)) : 0;
    }
    __syncthreads();
    for (int j = s + threadIdx.x; j < e; j += 256) {
        int c = cols[j];
        int pos = atomicAdd(&cur[c >> 7], 1);
        pedge[pos] = (rows[j] << 7) | (c & 127);
    }
}

__global__ __launch_bounds__(256)
void bucket_sort_kernel(const int* __restrict__ gcursor, const int* __restrict__ pedge,
                        int* __restrict__ srow, int* __restrict__ offsets,
                        int* __restrict__ deg) {
    __shared__ int cnt[128];
    __shared__ int scn[128];
    __shared__ int cur[128];
    int b = blockIdx.x, t = threadIdx.x;
    if (t < 128) cnt[t] = 0;
    __syncthreads();
    int e0 = b * BCAP;
    int tot = min(gcursor[b], BCAP);
    int e1 = e0 + tot;
    for (int j = e0 + t; j < e1; j += 256)
        atomicAdd(&cnt[pedge[j] & 127], 1);
    __syncthreads();
    if (t < 128) scn[t] = cnt[t];
    __syncthreads();
    for (int off = 1; off < 128; off <<= 1) {
        int v = 0;
        if (t < 128 && t >= off) v = scn[t - off];
        __syncthreads();
        if (t < 128) scn[t] += v;
        __syncthreads();
    }
    if (t < 128) {
        int excl = (t > 0) ? scn[t - 1] : 0;
        cur[t] = excl;
        int node = b * 128 + t;
        if (node < N_NODES) {
            offsets[node] = e0 + excl;
            deg[node] = cnt[t];
        }
    }
    __syncthreads();
    for (int j = e0 + t; j < e1; j += 256) {
        int p = pedge[j];
        int pos = atomicAdd(&cur[p & 127], 1);
        srow[e0 + pos] = p >> 7;
    }
}

// ---------------- MFMA GEMM, direct A-frags + global WT + FAT epilogue (R6-verified; deg form) ----------------

template<int K, int C1, int C2>
__launch_bounds__(256, 6)
__global__ void gemm_fat_kernel(const float* __restrict__ X,
                                const unsigned short* __restrict__ WT, // bf16 [CT][K]
                                const float* __restrict__ Bias,
                                const int* __restrict__ deg,
                                unsigned short* __restrict__ Y1b, // bf16 [N][C1]
                                float* __restrict__ Y2, int N) {
    constexpr int CT = C1 + C2;
    constexpr int NT = CT / 16;            // 16-col tiles
    constexpr int KS = K / 32;             // k-steps
    constexpr int S16 = 72;                // u16 epi row stride (144 B)
    constexpr int SF  = 68;                // f32 epi row stride (272 B)
    static_assert(CT % 16 == 0 && K % 32 == 0 && C1 % 8 == 0 && C2 % 4 == 0, "shape");

    __shared__ unsigned short eb16[4 * 16 * S16];  // 9216 B
    __shared__ float          ebf [4 * 16 * SF];   // 17408 B

    const int tid = threadIdx.x;
    const int wave = tid >> 6;
    const int lane = tid & 63;
    const int m = lane & 15;
    const int quad = lane >> 4;
    const int r0 = blockIdx.x * 64;

    const int rowA = r0 + wave * 16 + m;
    const bool va = (rowA < N);
    const float* xr = X + (size_t)rowA * K + quad * 8;

    union AFrag { uint4 u; bf16x8 v; } af[KS];
#pragma unroll
    for (int ks = 0; ks < KS; ++ks) {
        float4 v0 = make_float4(0.f, 0.f, 0.f, 0.f);
        float4 v1 = make_float4(0.f, 0.f, 0.f, 0.f);
        if (va) {
            v0 = *reinterpret_cast<const float4*>(xr + ks * 32);
            v1 = *reinterpret_cast<const float4*>(xr + ks * 32 + 4);
        }
        af[ks].u.x = pack_bf2(v0.x, v0.y);
        af[ks].u.y = pack_bf2(v0.z, v0.w);
        af[ks].u.z = pack_bf2(v1.x, v1.y);
        af[ks].u.w = pack_bf2(v1.z, v1.w);
    }

    f32x4 acc[NT];
#pragma unroll
    for (int t = 0; t < NT; ++t) acc[t] = (f32x4){0.f, 0.f, 0.f, 0.f};
#pragma unroll
    for (int ks = 0; ks < KS; ++ks) {
#pragma unroll
        for (int t = 0; t < NT; ++t) {
            bf16x8 b = *reinterpret_cast<const bf16x8*>(&WT[(size_t)(t * 16 + m) * K + ks * 32 + quad * 8]);
            acc[t] = __builtin_amdgcn_mfma_f32_16x16x32_bf16(af[ks].v, b, acc[t], 0, 0, 0);
        }
    }

    const int rbase0 = r0 + wave * 16;
    const int rbase = rbase0 + quad * 4;
    float dv[4];
#pragma unroll
    for (int reg = 0; reg < 4; ++reg)
        dv[reg] = (rbase + reg < N) ? dinv_of(deg[rbase + reg]) : 0.f;

    unsigned short* e16 = &eb16[wave * 16 * S16];
    float* ef = &ebf[wave * 16 * SF];
#pragma unroll
    for (int t = 0; t < NT; ++t) {
        int c = t * 16 + m;
        if (c < C1) {
#pragma unroll
            for (int reg = 0; reg < 4; ++reg)
                e16[(quad * 4 + reg) * S16 + c] = bf16_of(acc[t][reg] * dv[reg]);
        } else {
            float b = Bias[c - C1];
#pragma unroll
            for (int reg = 0; reg < 4; ++reg)
                ef[(quad * 4 + reg) * SF + (c - C1)] = acc[t][reg] + b;
        }
    }
    __syncthreads();

    constexpr int SEG1 = C1 / 8;
    for (int it = 0; it < (16 * SEG1 + 63) / 64; ++it) {
        int task = lane + it * 64;
        if (task < 16 * SEG1) {
            int row = task / SEG1, seg = task - row * SEG1;
            int gr = rbase0 + row;
            if (gr < N) {
                uint4 v = *reinterpret_cast<const uint4*>(&eb16[(wave * 16 + row) * S16 + seg * 8]);
                *reinterpret_cast<uint4*>(&Y1b[(size_t)gr * C1 + seg * 8]) = v;
            }
        }
    }
    constexpr int SEG2 = C2 / 4;
    for (int it = 0; it < (16 * SEG2 + 63) / 64; ++it) {
        int task = lane + it * 64;
        if (task < 16 * SEG2) {
            int row = task / SEG2, seg = task - row * SEG2;
            int gr = rbase0 + row;
            if (gr < N) {
                float4 v = *reinterpret_cast<const float4*>(&ebf[(wave * 16 + row) * SF + seg * 4]);
                *reinterpret_cast<float4*>(&Y2[(size_t)gr * C2 + seg * 4]) = v;
            }
        }
    }
}

// ---------------- FUSED pull L1 + layer-2 GEMM (R7-verified; deg form, nullable offsets) ----------------

__global__ __launch_bounds__(256)
void pull_gemm_fused_kernel(const int* __restrict__ offsets,
                            const int* __restrict__ deg,
                            const int* __restrict__ srow,
                            const unsigned* __restrict__ H,     // bf16 [N][64] pre-scaled
                            const float* __restrict__ Yp,       // f32 [N][64] partial (x@W1root+b1)
                            const unsigned short* __restrict__ WT2, // bf16 [80][64] (wtgB)
                            const float* __restrict__ Bias2,
                            unsigned short* __restrict__ H2,    // bf16 [N][40], dinv-scaled
                            float* __restrict__ Outp,           // f32 [N][40] partial
                            int N) {
    constexpr int KP = 36;                    // dwords per LDS h1 row (64+8 bf16)
    __shared__ unsigned xb[16 * KP];          // 2304 B
    __shared__ unsigned short e16[16 * 48];   // 1536 B
    __shared__ float epif[16 * 44];           // 2816 B

    const int tid = threadIdx.x;
    const int node16 = tid >> 4;
    const int lane16 = tid & 15;
    const int gnode = blockIdx.x * 16 + node16;

    // ---- phase 1: pull aggregation ----
    float4 h1 = make_float4(0.f, 0.f, 0.f, 0.f);
    if (gnode < N) {
        int dtrue = deg[gnode];
        int d = offsets ? dtrue : min(dtrue, NODE_CAP);
        int e0 = offsets ? offsets[gnode] : gnode * NODE_CAP;
        int e1 = e0 + d;
        float dc = dinv_of(dtrue);
        float4 acc = make_float4(0.f, 0.f, 0.f, 0.f);
        int j = e0;
        for (; j + 4 <= e1; j += 4) {
            int r0 = srow[j + 0];
            int r1 = srow[j + 1];
            int r2 = srow[j + 2];
            int r3 = srow[j + 3];
            uint2 u0 = *reinterpret_cast<const uint2*>(&H[(size_t)r0 * 32 + lane16 * 2]);
            uint2 u1 = *reinterpret_cast<const uint2*>(&H[(size_t)r1 * 32 + lane16 * 2]);
            uint2 u2 = *reinterpret_cast<const uint2*>(&H[(size_t)r2 * 32 + lane16 * 2]);
            uint2 u3 = *reinterpret_cast<const uint2*>(&H[(size_t)r3 * 32 + lane16 * 2]);
            acc.x += (bf_lo(u0.x) + bf_lo(u1.x)) + (bf_lo(u2.x) + bf_lo(u3.x));
            acc.y += (bf_hi(u0.x) + bf_hi(u1.x)) + (bf_hi(u2.x) + bf_hi(u3.x));
            acc.z += (bf_lo(u0.y) + bf_lo(u1.y)) + (bf_lo(u2.y) + bf_lo(u3.y));
            acc.w += (bf_hi(u0.y) + bf_hi(u1.y)) + (bf_hi(u2.y) + bf_hi(u3.y));
        }
        for (; j < e1; ++j) {
            int r = srow[j];
            uint2 u = *reinterpret_cast<const uint2*>(&H[(size_t)r * 32 + lane16 * 2]);
            acc.x += bf_lo(u.x);
            acc.y += bf_hi(u.x);
            acc.z += bf_lo(u.y);
            acc.w += bf_hi(u.y);
        }
        float4 y = *reinterpret_cast<const float4*>(&Yp[(size_t)gnode * 64 + lane16 * 4]);
        h1.x = fmaxf(fmaf(dc, acc.x, y.x), 0.f);
        h1.y = fmaxf(fmaf(dc, acc.y, y.y), 0.f);
        h1.z = fmaxf(fmaf(dc, acc.z, y.z), 0.f);
        h1.w = fmaxf(fmaf(dc, acc.w, y.w), 0.f);
    }
    xb[node16 * KP + lane16 * 2]     = pack_bf2(h1.x, h1.y);
    xb[node16 * KP + lane16 * 2 + 1] = pack_bf2(h1.z, h1.w);
    __syncthreads();

    // ---- phase 2: tiny GEMM 16x64 @ 64x80 ----
    const int wave = tid >> 6;
    const int lane = tid & 63;
    const int m = lane & 15;
    const int quad = lane >> 4;
    const int rb = blockIdx.x * 16 + quad * 4;

    float dv[4];
#pragma unroll
    for (int reg = 0; reg < 4; ++reg)
        dv[reg] = (rb + reg < N) ? dinv_of(deg[rb + reg]) : 0.f;

    bf16x8 a0 = *reinterpret_cast<const bf16x8*>(&xb[m * KP + 0 * 16 + quad * 4]);
    bf16x8 a1 = *reinterpret_cast<const bf16x8*>(&xb[m * KP + 1 * 16 + quad * 4]);

#pragma unroll
    for (int tt = 0; tt < 2; ++tt) {
        int t = wave + tt * 4;              // wave 0: tiles 0,4; waves 1-3: tiles 1-3
        if (t >= 5) break;                  // wave-uniform; no barrier inside loop
        bf16x8 b0 = *reinterpret_cast<const bf16x8*>(&WT2[(t * 16 + m) * 64 + 0 * 32 + quad * 8]);
        bf16x8 b1 = *reinterpret_cast<const bf16x8*>(&WT2[(t * 16 + m) * 64 + 1 * 32 + quad * 8]);
        f32x4 acc2 = (f32x4){0.f, 0.f, 0.f, 0.f};
        acc2 = __builtin_amdgcn_mfma_f32_16x16x32_bf16(a0, b0, acc2, 0, 0, 0);
        acc2 = __builtin_amdgcn_mfma_f32_16x16x32_bf16(a1, b1, acc2, 0, 0, 0);
        int c = t * 16 + m;
        if (c < 40) {
#pragma unroll
            for (int reg = 0; reg < 4; ++reg)
                e16[(quad * 4 + reg) * 48 + c] = bf16_of(acc2[reg] * dv[reg]);
        } else {
            float bb = Bias2[c - 40];
#pragma unroll
            for (int reg = 0; reg < 4; ++reg)
                epif[(quad * 4 + reg) * 44 + (c - 40)] = acc2[reg] + bb;
        }
    }
    __syncthreads();

    // ---- phase 3: fat cooperative stores ----
    if (tid < 80) {                         // H2: 16 rows x 5 x 16B segs
        int row = tid / 5, seg = tid - row * 5;
        int gr = blockIdx.x * 16 + row;
        if (gr < N) {
            uint4 v = *reinterpret_cast<const uint4*>(&e16[row * 48 + seg * 8]);
            *reinterpret_cast<uint4*>(&H2[(size_t)gr * 40 + seg * 8]) = v;
        }
    }
    if (tid < 160) {                        // Outp: 16 rows x 10 x 16B segs
        int row = tid / 10, seg = tid - row * 10;
        int gr = blockIdx.x * 16 + row;
        if (gr < N) {
            float4 v = *reinterpret_cast<const float4*>(&epif[row * 44 + seg * 4]);
            *reinterpret_cast<float4*>(&Outp[(size_t)gr * 40 + seg * 4]) = v;
        }
    }
}

// ---------------- fallback MFMA fused GEMM (in-kernel W staging; deg form) ----------------

template<int K, int C1, int C2>
__launch_bounds__(256)
__global__ void gemm_mfma_fused_kernel(const float* __restrict__ X,
                                       const float* __restrict__ W1,
                                       const float* __restrict__ W2,
                                       const float* __restrict__ Bias,
                                       const int* __restrict__ deg,
                                       unsigned short* __restrict__ Y1b, // bf16 [N][C1]
                                       float* __restrict__ Y2, int N) {
    constexpr int CT = C1 + C2;
    constexpr int NT = CT / 16;
    constexpr int KS = K / 32;
    constexpr int KP = (K + 8) / 2;
    static_assert(CT % 16 == 0 && K % 32 == 0, "shape");
    static_assert(C1 % 4 == 0 && C2 % 4 == 0, "staging vec4");

    __shared__ unsigned xb[64 * KP];
    __shared__ unsigned wt[CT * KP];
    __shared__ float dloc[64];

    const int tid = threadIdx.x;
    const int wave = tid >> 6;
    const int lane = tid & 63;
    const int m = lane & 15;
    const int quad = lane >> 4;
    const int r0 = blockIdx.x * 64;

    if (tid < 64) {
        int gr = r0 + tid;
        dloc[tid] = (gr < N) ? dinv_of(deg[gr]) : 0.f;
    }

    constexpr int XIT = 64 * (K / 4);
    for (int i = tid; i < XIT; i += 256) {
        int rr = i / (K / 4);
        int k4 = i - rr * (K / 4);
        int gr = r0 + rr;
        float4 v = make_float4(0.f, 0.f, 0.f, 0.f);
        if (gr < N)
            v = *reinterpret_cast<const float4*>(&X[(size_t)gr * K + k4 * 4]);
        uint2 p;
        p.x = pack_bf2(v.x, v.y);
        p.y = pack_bf2(v.z, v.w);
        *reinterpret_cast<uint2*>(&xb[rr * KP + k4 * 2]) = p;
    }

    constexpr int WIT = (K / 2) * (CT / 4);
    for (int i = tid; i < WIT; i += 256) {
        int kp = i / (CT / 4);
        int c4 = i - kp * (CT / 4);
        int k = kp * 2;
        int c = c4 * 4;
        float4 va, vb;
        if (c < C1) {
            va = *reinterpret_cast<const float4*>(&W1[(size_t)k * C1 + c]);
            vb = *reinterpret_cast<const float4*>(&W1[(size_t)(k + 1) * C1 + c]);
        } else {
            va = *reinterpret_cast<const float4*>(&W2[(size_t)k * C2 + (c - C1)]);
            vb = *reinterpret_cast<const float4*>(&W2[(size_t)(k + 1) * C2 + (c - C1)]);
        }
        wt[(c + 0) * KP + kp] = pack_bf2(va.x, vb.x);
        wt[(c + 1) * KP + kp] = pack_bf2(va.y, vb.y);
        wt[(c + 2) * KP + kp] = pack_bf2(va.z, vb.z);
        wt[(c + 3) * KP + kp] = pack_bf2(va.w, vb.w);
    }
    __syncthreads();

    const int rowbase = wave * 16;
    f32x4 acc[NT];
#pragma unroll
    for (int t = 0; t < NT; ++t) acc[t] = (f32x4){0.f, 0.f, 0.f, 0.f};

#pragma unroll
    for (int ks = 0; ks < KS; ++ks) {
        bf16x8 a = *reinterpret_cast<const bf16x8*>(&xb[(rowbase + m) * KP + ks * 16 + quad * 4]);
#pragma unroll
        for (int t = 0; t < NT; ++t) {
            bf16x8 b = *reinterpret_cast<const bf16x8*>(&wt[(t * 16 + m) * KP + ks * 16 + quad * 4]);
            acc[t] = __builtin_amdgcn_mfma_f32_16x16x32_bf16(a, b, acc[t], 0, 0, 0);
        }
    }

#pragma unroll
    for (int t = 0; t < NT; ++t) {
        int c = t * 16 + m;
        float bias = (c >= C1) ? Bias[c - C1] : 0.f;
#pragma unroll
        for (int reg = 0; reg < 4; ++reg) {
            int rl = rowbase + quad * 4 + reg;
            int r = r0 + rl;
            if (r >= N) continue;
            float v = acc[t][reg];
            if (c < C1) {
                Y1b[(size_t)r * C1 + c] = bf16_of(v * dloc[rl]);
            } else {
                Y2[(size_t)r * C2 + (c - C1)] = v + bias;
            }
        }
    }
}

// ---------------- pull aggregation over pre-scaled bf16 H (deg form, nullable offsets) ----------------

template<int C>
__launch_bounds__(256)
__global__ void pull_bf16_kernel(const int* __restrict__ offsets,
                                 const int* __restrict__ deg,
                                 const int* __restrict__ srow,
                                 const unsigned* __restrict__ H,   // bf16 [N][C], pre-scaled
                                 float* __restrict__ Y, int N) {
    constexpr int TPE = C / 4;             // lanes per node, 4 bf16 (uint2) each
    constexpr int CH = C / 2;              // uints per row
    int gid = blockIdx.x * blockDim.x + threadIdx.x;
    int node = gid / TPE;
    int lane = gid - node * TPE;
    if (node >= N) return;

    int dtrue = deg[node];
    int d = offsets ? dtrue : min(dtrue, NODE_CAP);
    int e0 = offsets ? offsets[node] : node * NODE_CAP;
    int e1 = e0 + d;
    float dc = dinv_of(dtrue);

    float4 acc = make_float4(0.f, 0.f, 0.f, 0.f);
    int j = e0;
    for (; j + 4 <= e1; j += 4) {
        int r0 = srow[j + 0];
        int r1 = srow[j + 1];
        int r2 = srow[j + 2];
        int r3 = srow[j + 3];
        uint2 u0 = *reinterpret_cast<const uint2*>(&H[(size_t)r0 * CH + lane * 2]);
        uint2 u1 = *reinterpret_cast<const uint2*>(&H[(size_t)r1 * CH + lane * 2]);
        uint2 u2 = *reinterpret_cast<const uint2*>(&H[(size_t)r2 * CH + lane * 2]);
        uint2 u3 = *reinterpret_cast<const uint2*>(&H[(size_t)r3 * CH + lane * 2]);
        acc.x += (bf_lo(u0.x) + bf_lo(u1.x)) + (bf_lo(u2.x) + bf_lo(u3.x));
        acc.y += (bf_hi(u0.x) + bf_hi(u1.x)) + (bf_hi(u2.x) + bf_hi(u3.x));
        acc.z += (bf_lo(u0.y) + bf_lo(u1.y)) + (bf_lo(u2.y) + bf_lo(u3.y));
        acc.w += (bf_hi(u0.y) + bf_hi(u1.y)) + (bf_hi(u2.y) + bf_hi(u3.y));
    }
    for (; j < e1; ++j) {
        int r = srow[j];
        uint2 u = *reinterpret_cast<const uint2*>(&H[(size_t)r * CH + lane * 2]);
        acc.x += bf_lo(u.x);
        acc.y += bf_hi(u.x);
        acc.z += bf_lo(u.y);
        acc.w += bf_hi(u.y);
    }

    float4* Y4 = reinterpret_cast<float4*>(Y);
    size_t yi = (size_t)node * TPE + lane;
    float4 y = Y4[yi];
    y.x = fmaxf(fmaf(dc, acc.x, y.x), 0.f);
    y.y = fmaxf(fmaf(dc, acc.y, y.y), 0.f);
    y.z = fmaxf(fmaf(dc, acc.z, y.z), 0.f);
    y.w = fmaxf(fmaf(dc, acc.w, y.w), 0.f);
    Y4[yi] = y;
}

// ---------------- launcher ----------------

extern "C" void kernel_launch(void* const* d_in, const int* in_sizes, int n_in,
                              void* d_out, int out_size, void* d_ws, size_t ws_size,
                              hipStream_t stream) {
    const float* x       = (const float*)d_in[0];
    const int*   eidx    = (const int*)d_in[1];
    const float* w1_init = (const float*)d_in[2];
    const float* w1_root = (const float*)d_in[3];
    const float* b1      = (const float*)d_in[4];
    const float* w2_init = (const float*)d_in[5];
    const float* w2_root = (const float*)d_in[6];
    const float* b2      = (const float*)d_in[7];
    float* out = (float*)d_out;

    const int* rows = eidx;                // edge_index[0] (source)
    const int* cols = eidx + N_EDGES;      // edge_index[1] (target)

    int* wsi = (int*)d_ws;
    const int NTILES = cdiv(N_NODES, 64);  // 1563

    // ---- tier A: direct per-node CSR (no buckets/sort), 62.85 MB ----
    {
        int*      degA  = wsi;                          //   100,000
        int*      srowA = wsi + 100000;                 // 4,000,000 (N*NODE_CAP)
        unsigned* h0b   = (unsigned*)(wsi + 4100000);   // 3,200,000
        float*    agg1  = (float*)(wsi + 7300000);      // 6,400,000
        unsigned* wtgA  = (unsigned*)(wsi + 13700000);  //     8,192
        unsigned* wtgB  = wtgA + 8192;                  //     2,560
        unsigned short* h2s = (unsigned short*)(wsi + 13710752); // 2,000,000 dw
        const size_t WS_DIR = 15710752ull * 4ull;       // 62.85 MB

        if (ws_size >= WS_DIR) {
            hipMemsetAsync(degA, 0, N_NODES * sizeof(int), stream);
            scatter_direct_wconv_kernel<<<SCATG + 43, 256, 0, stream>>>(
                rows, cols, degA, srowA, N_EDGES,
                w1_init, w1_root, w2_init, w2_root, wtgA, wtgB);

            gemm_fat_kernel<IN_CH, HID_CH, HID_CH><<<NTILES, 256, 0, stream>>>(
                x, (const unsigned short*)wtgA, b1, degA, (unsigned short*)h0b, agg1, N_NODES);
            pull_gemm_fused_kernel<<<cdiv(N_NODES, 16), 256, 0, stream>>>(
                nullptr, degA, srowA, h0b, agg1, (const unsigned short*)wtgB, b2,
                h2s, out, N_NODES);
            pull_bf16_kernel<N_CLS><<<cdiv(N_NODES * (N_CLS / 4), 256), 256, 0, stream>>>(
                nullptr, degA, srowA, (const unsigned*)h2s, out, N_NODES);
            return;
        }
    }

    // ---- fallback tiers: R10 padded-bucket scheme ----
    int*      gcursor = wsi;                         //     788
    int*      offsets = wsi + 100788;                //   100,004
    int*      deg     = wsi + 200792;                //   100,000
    int*      srow    = wsi + 300792;                // 1,301,248 (NBUCK*BCAP)
    unsigned* h0b     = (unsigned*)(wsi + 1602040);  // 3,200,000
    int*      pedge   = wsi + 1602040;               // aliases h0b: dead before gemm L1
    float*    agg1    = (float*)(wsi + 4802040);     // 6,400,000
    unsigned* h2b     = h0b;
    unsigned* wtgA    = (unsigned*)(wsi + 11202040); //     8,192
    unsigned* wtgB    = wtgA + 8192;                 //     2,560
    unsigned short* h2s = (unsigned short*)(wsi + 11212792); // 2,000,000 dw
    const size_t WS_C = 11212792ull * 4ull;          // 44.85 MB
    const size_t WS_B = 13212792ull * 4ull;          // 52.85 MB

    const bool have_wt = (ws_size >= WS_C);
    unsigned* wtgA_arg = have_wt ? wtgA : nullptr;
    unsigned* wtgB_arg = have_wt ? wtgB : nullptr;

    hipMemsetAsync(gcursor, 0, 788 * sizeof(int), stream);
    bucket_scatter_wconv_kernel<<<NCOUNT + 43, 256, 0, stream>>>(
        rows, cols, gcursor, pedge, N_EDGES,
        w1_init, w1_root, w2_init, w2_root, wtgA_arg, wtgB_arg);
    bucket_sort_kernel<<<NBUCK, 256, 0, stream>>>(gcursor, pedge, srow, offsets, deg);

    if (ws_size >= WS_B) {
        gemm_fat_kernel<IN_CH, HID_CH, HID_CH><<<NTILES, 256, 0, stream>>>(
            x, (const unsigned short*)wtgA, b1, deg, (unsigned short*)h0b, agg1, N_NODES);
        pull_gemm_fused_kernel<<<cdiv(N_NODES, 16), 256, 0, stream>>>(
            offsets, deg, srow, h0b, agg1, (const unsigned short*)wtgB, b2,
            h2s, out, N_NODES);
        pull_bf16_kernel<N_CLS><<<cdiv(N_NODES * (N_CLS / 4), 256), 256, 0, stream>>>(
            offsets, deg, srow, (const unsigned*)h2s, out, N_NODES);
    } else if (have_wt) {
        gemm_fat_kernel<IN_CH, HID_CH, HID_CH><<<NTILES, 256, 0, stream>>>(
            x, (const unsigned short*)wtgA, b1, deg, (unsigned short*)h0b, agg1, N_NODES);
        pull_bf16_kernel<HID_CH><<<cdiv(N_NODES * (HID_CH / 4), 256), 256, 0, stream>>>(
            offsets, deg, srow, h0b, agg1, N_NODES);
        gemm_fat_kernel<HID_CH, N_CLS, N_CLS><<<NTILES, 256, 0, stream>>>(
            agg1, (const unsigned short*)wtgB, b2, deg, (unsigned short*)h2b, out, N_NODES);
        pull_bf16_kernel<N_CLS><<<cdiv(N_NODES * (N_CLS / 4), 256), 256, 0, stream>>>(
            offsets, deg, srow, h2b, out, N_NODES);
    } else {
        gemm_mfma_fused_kernel<IN_CH, HID_CH, HID_CH><<<NTILES, 256, 0, stream>>>(
            x, w1_init, w1_root, b1, deg, (unsigned short*)h0b, agg1, N_NODES);
        pull_bf16_kernel<HID_CH><<<cdiv(N_NODES * (HID_CH / 4), 256), 256, 0, stream>>>(
            offsets, deg, srow, h0b, agg1, N_NODES);
        gemm_mfma_fused_kernel<HID_CH, N_CLS, N_CLS><<<NTILES, 256, 0, stream>>>(
            agg1, w2_init, w2_root, b2, deg, (unsigned short*)h2b, out, N_NODES);
        pull_bf16_kernel<N_CLS><<<cdiv(N_NODES * (N_CLS / 4), 256), 256, 0, stream>>>(
            offsets, deg, srow, h2b, out, N_NODES);
    }
}

// Round 13
// 231.735 us; speedup vs baseline: 1.1783x; 1.1783x over previous
//
#include <hip/hip_runtime.h>

#define N_NODES 100000
#define N_EDGES 1000000
#define IN_CH 128
#define HID_CH 64
#define N_CLS 40

#define NBUCK 782              // ceil(100000 / 128) buckets of 128 target cols
#define BCAP 1664              // padded bucket capacity (mean 1279 + 10.7 sigma)
#define NCOUNT 256             // scatter grid (per-block LDS hist scheme is grid-agnostic)

static inline int cdiv(int a, int b) { return (a + b - 1) / b; }

using bf16x8 = __attribute__((ext_vector_type(8))) short;   // 8 bf16 (4 VGPRs)
using f32x4  = __attribute__((ext_vector_type(4))) float;   // MFMA accumulator

// RNE float->bf16 pack (a in low 16, b in high 16)
__device__ __forceinline__ unsigned pack_bf2(float a, float b) {
    unsigned ua = __float_as_uint(a), ub = __float_as_uint(b);
    ua += 0x7fffu + ((ua >> 16) & 1u);
    ub += 0x7fffu + ((ub >> 16) & 1u);
    return (ua >> 16) | (ub & 0xffff0000u);
}
__device__ __forceinline__ unsigned short bf16_of(float a) {
    unsigned ua = __float_as_uint(a);
    ua += 0x7fffu + ((ua >> 16) & 1u);
    return (unsigned short)(ua >> 16);
}
__device__ __forceinline__ float bf_lo(unsigned u) { return __uint_as_float(u << 16); }
__device__ __forceinline__ float bf_hi(unsigned u) { return __uint_as_float(u & 0xffff0000u); }
__device__ __forceinline__ float dinv_of(int d) { return d ? rsqrtf((float)d) : 0.f; }

// ---------------- device helper: one-time wconv work item ----------------
// wtgA [128][128]: c<64 -> w1_init col c ; c>=64 -> w1_root col c-64   (K=128)
// wtgB [80][64]:   c<40 -> w2_init col c ; c>=40 -> w2_root col c-40   (K=64)

__device__ __forceinline__ void wconv_item(int id,
                                           const float* __restrict__ w1i, const float* __restrict__ w1r,
                                           const float* __restrict__ w2i, const float* __restrict__ w2r,
                                           unsigned* __restrict__ wtgA, unsigned* __restrict__ wtgB) {
    if (id < 128 * 64) {                    // wtgA: 128 cols x 64 k-pairs
        int c = id >> 6, kp = id & 63;
        int k = kp * 2;
        const float* W = (c < 64) ? w1i : w1r;
        int cc = (c < 64) ? c : c - 64;
        float a = W[(size_t)k * 64 + cc];
        float b = W[(size_t)(k + 1) * 64 + cc];
        wtgA[c * 64 + kp] = pack_bf2(a, b);
    } else if (id < 128 * 64 + 80 * 32) {   // wtgB: 80 cols x 32 k-pairs
        int j = id - 128 * 64;
        int c = j >> 5, kp = j & 31;
        int k = kp * 2;
        const float* W = (c < 40) ? w2i : w2r;
        int cc = (c < 40) ? c : c - 40;
        float a = W[(size_t)k * 40 + cc];
        float b = W[(size_t)(k + 1) * 40 + cc];
        wtgB[c * 32 + kp] = pack_bf2(a, b);
    }
}

// ---------------- scatter into PADDED buckets (R10-verified) + fused wconv ----------------
// R11/R12 lesson: direct per-node scatter with global returning atomics is
// structurally worse (54-78us; device-scope atomics to a hot 400KB counter
// array don't scale with concurrency across non-coherent XCD L2s). The
// bucket scheme batches reservations per-block via LDS and is the best of
// three measured prep structures. Fixed-capacity buckets (base = b*BCAP):
// no count/scan dispatches. P(bucket>1664) ~ 1e-24 for 1M uniform edges.

__global__ __launch_bounds__(256)
void bucket_scatter_wconv_kernel(const int* __restrict__ rows, const int* __restrict__ cols,
                                 int* __restrict__ gcursor, int* __restrict__ pedge, int E,
                                 const float* __restrict__ w1i, const float* __restrict__ w1r,
                                 const float* __restrict__ w2i, const float* __restrict__ w2r,
                                 unsigned* __restrict__ wtgA, unsigned* __restrict__ wtgB) {
    if (blockIdx.x >= NCOUNT) {            // wconv part (block-uniform branch)
        if (wtgA == nullptr) return;
        wconv_item((blockIdx.x - NCOUNT) * 256 + threadIdx.x, w1i, w1r, w2i, w2r, wtgA, wtgB);
        return;
    }
    __shared__ int cur[NBUCK];
    for (int i = threadIdx.x; i < NBUCK; i += 256) cur[i] = 0;
    __syncthreads();
    int per = (E + NCOUNT - 1) / NCOUNT;
    int s = blockIdx.x * per;
    int e = min(E, s + per);
    for (int j = s + threadIdx.x; j < e; j += 256)
        atomicAdd(&cur[cols[j] >> 7], 1);
    __syncthreads();
    for (int i = threadIdx.x; i < NBUCK; i += 256) {
        int h = cur[i];
        cur[i] = h ? (i * BCAP + atomicAdd(&gcursor[i], h)) : 0;
    }
    __syncthreads();
    for (int j = s + threadIdx.x; j < e; j += 256) {
        int c = cols[j];
        int pos = atomicAdd(&cur[c >> 7], 1);     // LDS returning atomic, absolute index
        pedge[pos] = (rows[j] << 7) | (c & 127);
    }
}

// ---------------- per-bucket counting sort -> srow (padded CSR), offsets, deg ----------------

__global__ __launch_bounds__(256)
void bucket_sort_kernel(const int* __restrict__ gcursor, const int* __restrict__ pedge,
                        int* __restrict__ srow, int* __restrict__ offsets,
                        int* __restrict__ deg) {
    __shared__ int cnt[128];
    __shared__ int scn[128];
    __shared__ int cur[128];
    int b = blockIdx.x, t = threadIdx.x;
    if (t < 128) cnt[t] = 0;
    __syncthreads();
    int e0 = b * BCAP;
    int tot = min(gcursor[b], BCAP);       // defensive clamp
    int e1 = e0 + tot;
    for (int j = e0 + t; j < e1; j += 256)
        atomicAdd(&cnt[pedge[j] & 127], 1);
    __syncthreads();
    if (t < 128) scn[t] = cnt[t];
    __syncthreads();
    for (int off = 1; off < 128; off <<= 1) {
        int v = 0;
        if (t < 128 && t >= off) v = scn[t - off];
        __syncthreads();
        if (t < 128) scn[t] += v;
        __syncthreads();
    }
    if (t < 128) {
        int excl = (t > 0) ? scn[t - 1] : 0;
        cur[t] = excl;
        int node = b * 128 + t;
        if (node < N_NODES) {
            offsets[node] = e0 + excl;
            deg[node] = cnt[t];
        }
    }
    __syncthreads();
    for (int j = e0 + t; j < e1; j += 256) {
        int p = pedge[j];
        int pos = atomicAdd(&cur[p & 127], 1);
        srow[e0 + pos] = p >> 7;
    }
}

// ---------------- MFMA GEMM, direct A-frags + global WT + FAT epilogue (R6/R12-verified; deg form) ----------------

template<int K, int C1, int C2>
__launch_bounds__(256, 6)
__global__ void gemm_fat_kernel(const float* __restrict__ X,
                                const unsigned short* __restrict__ WT, // bf16 [CT][K]
                                const float* __restrict__ Bias,
                                const int* __restrict__ deg,
                                unsigned short* __restrict__ Y1b, // bf16 [N][C1]
                                float* __restrict__ Y2, int N) {
    constexpr int CT = C1 + C2;
    constexpr int NT = CT / 16;            // 16-col tiles
    constexpr int KS = K / 32;             // k-steps
    constexpr int S16 = 72;                // u16 epi row stride (144 B)
    constexpr int SF  = 68;                // f32 epi row stride (272 B)
    static_assert(CT % 16 == 0 && K % 32 == 0 && C1 % 8 == 0 && C2 % 4 == 0, "shape");

    __shared__ unsigned short eb16[4 * 16 * S16];  // 9216 B
    __shared__ float          ebf [4 * 16 * SF];   // 17408 B

    const int tid = threadIdx.x;
    const int wave = tid >> 6;
    const int lane = tid & 63;
    const int m = lane & 15;
    const int quad = lane >> 4;
    const int r0 = blockIdx.x * 64;

    const int rowA = r0 + wave * 16 + m;
    const bool va = (rowA < N);
    const float* xr = X + (size_t)rowA * K + quad * 8;

    union AFrag { uint4 u; bf16x8 v; } af[KS];
#pragma unroll
    for (int ks = 0; ks < KS; ++ks) {
        float4 v0 = make_float4(0.f, 0.f, 0.f, 0.f);
        float4 v1 = make_float4(0.f, 0.f, 0.f, 0.f);
        if (va) {
            v0 = *reinterpret_cast<const float4*>(xr + ks * 32);
            v1 = *reinterpret_cast<const float4*>(xr + ks * 32 + 4);
        }
        af[ks].u.x = pack_bf2(v0.x, v0.y);
        af[ks].u.y = pack_bf2(v0.z, v0.w);
        af[ks].u.z = pack_bf2(v1.x, v1.y);
        af[ks].u.w = pack_bf2(v1.z, v1.w);
    }

    f32x4 acc[NT];
#pragma unroll
    for (int t = 0; t < NT; ++t) acc[t] = (f32x4){0.f, 0.f, 0.f, 0.f};
#pragma unroll
    for (int ks = 0; ks < KS; ++ks) {
#pragma unroll
        for (int t = 0; t < NT; ++t) {
            bf16x8 b = *reinterpret_cast<const bf16x8*>(&WT[(size_t)(t * 16 + m) * K + ks * 32 + quad * 8]);
            acc[t] = __builtin_amdgcn_mfma_f32_16x16x32_bf16(af[ks].v, b, acc[t], 0, 0, 0);
        }
    }

    const int rbase0 = r0 + wave * 16;
    const int rbase = rbase0 + quad * 4;
    float dv[4];
#pragma unroll
    for (int reg = 0; reg < 4; ++reg)
        dv[reg] = (rbase + reg < N) ? dinv_of(deg[rbase + reg]) : 0.f;

    unsigned short* e16 = &eb16[wave * 16 * S16];
    float* ef = &ebf[wave * 16 * SF];
#pragma unroll
    for (int t = 0; t < NT; ++t) {
        int c = t * 16 + m;
        if (c < C1) {
#pragma unroll
            for (int reg = 0; reg < 4; ++reg)
                e16[(quad * 4 + reg) * S16 + c] = bf16_of(acc[t][reg] * dv[reg]);
        } else {
            float b = Bias[c - C1];
#pragma unroll
            for (int reg = 0; reg < 4; ++reg)
                ef[(quad * 4 + reg) * SF + (c - C1)] = acc[t][reg] + b;
        }
    }
    __syncthreads();

    constexpr int SEG1 = C1 / 8;
    for (int it = 0; it < (16 * SEG1 + 63) / 64; ++it) {
        int task = lane + it * 64;
        if (task < 16 * SEG1) {
            int row = task / SEG1, seg = task - row * SEG1;
            int gr = rbase0 + row;
            if (gr < N) {
                uint4 v = *reinterpret_cast<const uint4*>(&eb16[(wave * 16 + row) * S16 + seg * 8]);
                *reinterpret_cast<uint4*>(&Y1b[(size_t)gr * C1 + seg * 8]) = v;
            }
        }
    }
    constexpr int SEG2 = C2 / 4;
    for (int it = 0; it < (16 * SEG2 + 63) / 64; ++it) {
        int task = lane + it * 64;
        if (task < 16 * SEG2) {
            int row = task / SEG2, seg = task - row * SEG2;
            int gr = rbase0 + row;
            if (gr < N) {
                float4 v = *reinterpret_cast<const float4*>(&ebf[(wave * 16 + row) * SF + seg * 4]);
                *reinterpret_cast<float4*>(&Y2[(size_t)gr * C2 + seg * 4]) = v;
            }
        }
    }
}

// ---------------- FUSED pull L1 + layer-2 GEMM (R7/R12-verified; deg form) ----------------

__global__ __launch_bounds__(256)
void pull_gemm_fused_kernel(const int* __restrict__ offsets,
                            const int* __restrict__ deg,
                            const int* __restrict__ srow,
                            const unsigned* __restrict__ H,     // bf16 [N][64] pre-scaled
                            const float* __restrict__ Yp,       // f32 [N][64] partial (x@W1root+b1)
                            const unsigned short* __restrict__ WT2, // bf16 [80][64] (wtgB)
                            const float* __restrict__ Bias2,
                            unsigned short* __restrict__ H2,    // bf16 [N][40], dinv-scaled
                            float* __restrict__ Outp,           // f32 [N][40] partial
                            int N) {
    constexpr int KP = 36;                    // dwords per LDS h1 row (64+8 bf16)
    __shared__ unsigned xb[16 * KP];          // 2304 B
    __shared__ unsigned short e16[16 * 48];   // 1536 B
    __shared__ float epif[16 * 44];           // 2816 B

    const int tid = threadIdx.x;
    const int node16 = tid >> 4;
    const int lane16 = tid & 15;
    const int gnode = blockIdx.x * 16 + node16;

    // ---- phase 1: pull aggregation ----
    float4 h1 = make_float4(0.f, 0.f, 0.f, 0.f);
    if (gnode < N) {
        int dtrue = deg[gnode];
        int e0 = offsets[gnode];
        int e1 = e0 + dtrue;
        float dc = dinv_of(dtrue);
        float4 acc = make_float4(0.f, 0.f, 0.f, 0.f);
        int j = e0;
        for (; j + 4 <= e1; j += 4) {
            int r0 = srow[j + 0];
            int r1 = srow[j + 1];
            int r2 = srow[j + 2];
            int r3 = srow[j + 3];
            uint2 u0 = *reinterpret_cast<const uint2*>(&H[(size_t)r0 * 32 + lane16 * 2]);
            uint2 u1 = *reinterpret_cast<const uint2*>(&H[(size_t)r1 * 32 + lane16 * 2]);
            uint2 u2 = *reinterpret_cast<const uint2*>(&H[(size_t)r2 * 32 + lane16 * 2]);
            uint2 u3 = *reinterpret_cast<const uint2*>(&H[(size_t)r3 * 32 + lane16 * 2]);
            acc.x += (bf_lo(u0.x) + bf_lo(u1.x)) + (bf_lo(u2.x) + bf_lo(u3.x));
            acc.y += (bf_hi(u0.x) + bf_hi(u1.x)) + (bf_hi(u2.x) + bf_hi(u3.x));
            acc.z += (bf_lo(u0.y) + bf_lo(u1.y)) + (bf_lo(u2.y) + bf_lo(u3.y));
            acc.w += (bf_hi(u0.y) + bf_hi(u1.y)) + (bf_hi(u2.y) + bf_hi(u3.y));
        }
        for (; j < e1; ++j) {
            int r = srow[j];
            uint2 u = *reinterpret_cast<const uint2*>(&H[(size_t)r * 32 + lane16 * 2]);
            acc.x += bf_lo(u.x);
            acc.y += bf_hi(u.x);
            acc.z += bf_lo(u.y);
            acc.w += bf_hi(u.y);
        }
        float4 y = *reinterpret_cast<const float4*>(&Yp[(size_t)gnode * 64 + lane16 * 4]);
        h1.x = fmaxf(fmaf(dc, acc.x, y.x), 0.f);
        h1.y = fmaxf(fmaf(dc, acc.y, y.y), 0.f);
        h1.z = fmaxf(fmaf(dc, acc.z, y.z), 0.f);
        h1.w = fmaxf(fmaf(dc, acc.w, y.w), 0.f);
    }
    xb[node16 * KP + lane16 * 2]     = pack_bf2(h1.x, h1.y);
    xb[node16 * KP + lane16 * 2 + 1] = pack_bf2(h1.z, h1.w);
    __syncthreads();

    // ---- phase 2: tiny GEMM 16x64 @ 64x80 ----
    const int wave = tid >> 6;
    const int lane = tid & 63;
    const int m = lane & 15;
    const int quad = lane >> 4;
    const int rb = blockIdx.x * 16 + quad * 4;

    float dv[4];
#pragma unroll
    for (int reg = 0; reg < 4; ++reg)
        dv[reg] = (rb + reg < N) ? dinv_of(deg[rb + reg]) : 0.f;

    bf16x8 a0 = *reinterpret_cast<const bf16x8*>(&xb[m * KP + 0 * 16 + quad * 4]);
    bf16x8 a1 = *reinterpret_cast<const bf16x8*>(&xb[m * KP + 1 * 16 + quad * 4]);

#pragma unroll
    for (int tt = 0; tt < 2; ++tt) {
        int t = wave + tt * 4;              // wave 0: tiles 0,4; waves 1-3: tiles 1-3
        if (t >= 5) break;                  // wave-uniform; no barrier inside loop
        bf16x8 b0 = *reinterpret_cast<const bf16x8*>(&WT2[(t * 16 + m) * 64 + 0 * 32 + quad * 8]);
        bf16x8 b1 = *reinterpret_cast<const bf16x8*>(&WT2[(t * 16 + m) * 64 + 1 * 32 + quad * 8]);
        f32x4 acc2 = (f32x4){0.f, 0.f, 0.f, 0.f};
        acc2 = __builtin_amdgcn_mfma_f32_16x16x32_bf16(a0, b0, acc2, 0, 0, 0);
        acc2 = __builtin_amdgcn_mfma_f32_16x16x32_bf16(a1, b1, acc2, 0, 0, 0);
        int c = t * 16 + m;
        if (c < 40) {
#pragma unroll
            for (int reg = 0; reg < 4; ++reg)
                e16[(quad * 4 + reg) * 48 + c] = bf16_of(acc2[reg] * dv[reg]);
        } else {
            float bb = Bias2[c - 40];
#pragma unroll
            for (int reg = 0; reg < 4; ++reg)
                epif[(quad * 4 + reg) * 44 + (c - 40)] = acc2[reg] + bb;
        }
    }
    __syncthreads();

    // ---- phase 3: fat cooperative stores ----
    if (tid < 80) {                         // H2: 16 rows x 5 x 16B segs
        int row = tid / 5, seg = tid - row * 5;
        int gr = blockIdx.x * 16 + row;
        if (gr < N) {
            uint4 v = *reinterpret_cast<const uint4*>(&e16[row * 48 + seg * 8]);
            *reinterpret_cast<uint4*>(&H2[(size_t)gr * 40 + seg * 8]) = v;
        }
    }
    if (tid < 160) {                        // Outp: 16 rows x 10 x 16B segs
        int row = tid / 10, seg = tid - row * 10;
        int gr = blockIdx.x * 16 + row;
        if (gr < N) {
            float4 v = *reinterpret_cast<const float4*>(&epif[row * 44 + seg * 4]);
            *reinterpret_cast<float4*>(&Outp[(size_t)gr * 40 + seg * 4]) = v;
        }
    }
}

// ---------------- fallback MFMA fused GEMM (in-kernel W staging; deg form) ----------------

template<int K, int C1, int C2>
__launch_bounds__(256)
__global__ void gemm_mfma_fused_kernel(const float* __restrict__ X,
                                       const float* __restrict__ W1,
                                       const float* __restrict__ W2,
                                       const float* __restrict__ Bias,
                                       const int* __restrict__ deg,
                                       unsigned short* __restrict__ Y1b, // bf16 [N][C1]
                                       float* __restrict__ Y2, int N) {
    constexpr int CT = C1 + C2;
    constexpr int NT = CT / 16;
    constexpr int KS = K / 32;
    constexpr int KP = (K + 8) / 2;
    static_assert(CT % 16 == 0 && K % 32 == 0, "shape");
    static_assert(C1 % 4 == 0 && C2 % 4 == 0, "staging vec4");

    __shared__ unsigned xb[64 * KP];
    __shared__ unsigned wt[CT * KP];
    __shared__ float dloc[64];

    const int tid = threadIdx.x;
    const int wave = tid >> 6;
    const int lane = tid & 63;
    const int m = lane & 15;
    const int quad = lane >> 4;
    const int r0 = blockIdx.x * 64;

    if (tid < 64) {
        int gr = r0 + tid;
        dloc[tid] = (gr < N) ? dinv_of(deg[gr]) : 0.f;
    }

    constexpr int XIT = 64 * (K / 4);
    for (int i = tid; i < XIT; i += 256) {
        int rr = i / (K / 4);
        int k4 = i - rr * (K / 4);
        int gr = r0 + rr;
        float4 v = make_float4(0.f, 0.f, 0.f, 0.f);
        if (gr < N)
            v = *reinterpret_cast<const float4*>(&X[(size_t)gr * K + k4 * 4]);
        uint2 p;
        p.x = pack_bf2(v.x, v.y);
        p.y = pack_bf2(v.z, v.w);
        *reinterpret_cast<uint2*>(&xb[rr * KP + k4 * 2]) = p;
    }

    constexpr int WIT = (K / 2) * (CT / 4);
    for (int i = tid; i < WIT; i += 256) {
        int kp = i / (CT / 4);
        int c4 = i - kp * (CT / 4);
        int k = kp * 2;
        int c = c4 * 4;
        float4 va, vb;
        if (c < C1) {
            va = *reinterpret_cast<const float4*>(&W1[(size_t)k * C1 + c]);
            vb = *reinterpret_cast<const float4*>(&W1[(size_t)(k + 1) * C1 + c]);
        } else {
            va = *reinterpret_cast<const float4*>(&W2[(size_t)k * C2 + (c - C1)]);
            vb = *reinterpret_cast<const float4*>(&W2[(size_t)(k + 1) * C2 + (c - C1)]);
        }
        wt[(c + 0) * KP + kp] = pack_bf2(va.x, vb.x);
        wt[(c + 1) * KP + kp] = pack_bf2(va.y, vb.y);
        wt[(c + 2) * KP + kp] = pack_bf2(va.z, vb.z);
        wt[(c + 3) * KP + kp] = pack_bf2(va.w, vb.w);
    }
    __syncthreads();

    const int rowbase = wave * 16;
    f32x4 acc[NT];
#pragma unroll
    for (int t = 0; t < NT; ++t) acc[t] = (f32x4){0.f, 0.f, 0.f, 0.f};

#pragma unroll
    for (int ks = 0; ks < KS; ++ks) {
        bf16x8 a = *reinterpret_cast<const bf16x8*>(&xb[(rowbase + m) * KP + ks * 16 + quad * 4]);
#pragma unroll
        for (int t = 0; t < NT; ++t) {
            bf16x8 b = *reinterpret_cast<const bf16x8*>(&wt[(t * 16 + m) * KP + ks * 16 + quad * 4]);
            acc[t] = __builtin_amdgcn_mfma_f32_16x16x32_bf16(a, b, acc[t], 0, 0, 0);
        }
    }

#pragma unroll
    for (int t = 0; t < NT; ++t) {
        int c = t * 16 + m;
        float bias = (c >= C1) ? Bias[c - C1] : 0.f;
#pragma unroll
        for (int reg = 0; reg < 4; ++reg) {
            int rl = rowbase + quad * 4 + reg;
            int r = r0 + rl;
            if (r >= N) continue;
            float v = acc[t][reg];
            if (c < C1) {
                Y1b[(size_t)r * C1 + c] = bf16_of(v * dloc[rl]);
            } else {
                Y2[(size_t)r * C2 + (c - C1)] = v + bias;
            }
        }
    }
}

// ---------------- pull aggregation over pre-scaled bf16 H (deg form) ----------------

template<int C>
__launch_bounds__(256)
__global__ void pull_bf16_kernel(const int* __restrict__ offsets,
                                 const int* __restrict__ deg,
                                 const int* __restrict__ srow,
                                 const unsigned* __restrict__ H,   // bf16 [N][C], pre-scaled
                                 float* __restrict__ Y, int N) {
    constexpr int TPE = C / 4;             // lanes per node, 4 bf16 (uint2) each
    constexpr int CH = C / 2;              // uints per row
    int gid = blockIdx.x * blockDim.x + threadIdx.x;
    int node = gid / TPE;
    int lane = gid - node * TPE;
    if (node >= N) return;

    int dtrue = deg[node];
    int e0 = offsets[node];
    int e1 = e0 + dtrue;
    float dc = dinv_of(dtrue);

    float4 acc = make_float4(0.f, 0.f, 0.f, 0.f);
    int j = e0;
    for (; j + 4 <= e1; j += 4) {
        int r0 = srow[j + 0];
        int r1 = srow[j + 1];
        int r2 = srow[j + 2];
        int r3 = srow[j + 3];
        uint2 u0 = *reinterpret_cast<const uint2*>(&H[(size_t)r0 * CH + lane * 2]);
        uint2 u1 = *reinterpret_cast<const uint2*>(&H[(size_t)r1 * CH + lane * 2]);
        uint2 u2 = *reinterpret_cast<const uint2*>(&H[(size_t)r2 * CH + lane * 2]);
        uint2 u3 = *reinterpret_cast<const uint2*>(&H[(size_t)r3 * CH + lane * 2]);
        acc.x += (bf_lo(u0.x) + bf_lo(u1.x)) + (bf_lo(u2.x) + bf_lo(u3.x));
        acc.y += (bf_hi(u0.x) + bf_hi(u1.x)) + (bf_hi(u2.x) + bf_hi(u3.x));
        acc.z += (bf_lo(u0.y) + bf_lo(u1.y)) + (bf_lo(u2.y) + bf_lo(u3.y));
        acc.w += (bf_hi(u0.y) + bf_hi(u1.y)) + (bf_hi(u2.y) + bf_hi(u3.y));
    }
    for (; j < e1; ++j) {
        int r = srow[j];
        uint2 u = *reinterpret_cast<const uint2*>(&H[(size_t)r * CH + lane * 2]);
        acc.x += bf_lo(u.x);
        acc.y += bf_hi(u.x);
        acc.z += bf_lo(u.y);
        acc.w += bf_hi(u.y);
    }

    float4* Y4 = reinterpret_cast<float4*>(Y);
    size_t yi = (size_t)node * TPE + lane;
    float4 y = Y4[yi];
    y.x = fmaxf(fmaf(dc, acc.x, y.x), 0.f);
    y.y = fmaxf(fmaf(dc, acc.y, y.y), 0.f);
    y.z = fmaxf(fmaf(dc, acc.z, y.z), 0.f);
    y.w = fmaxf(fmaf(dc, acc.w, y.w), 0.f);
    Y4[yi] = y;
}

// ---------------- launcher ----------------

extern "C" void kernel_launch(void* const* d_in, const int* in_sizes, int n_in,
                              void* d_out, int out_size, void* d_ws, size_t ws_size,
                              hipStream_t stream) {
    const float* x       = (const float*)d_in[0];
    const int*   eidx    = (const int*)d_in[1];
    const float* w1_init = (const float*)d_in[2];
    const float* w1_root = (const float*)d_in[3];
    const float* b1      = (const float*)d_in[4];
    const float* w2_init = (const float*)d_in[5];
    const float* w2_root = (const float*)d_in[6];
    const float* b2      = (const float*)d_in[7];
    float* out = (float*)d_out;

    const int* rows = eidx;                // edge_index[0] (source)
    const int* cols = eidx + N_EDGES;      // edge_index[1] (target)

    // workspace layout (4-byte units) -- R10-verified scheme
    int* wsi = (int*)d_ws;
    int*      gcursor = wsi;                         //     788
    int*      offsets = wsi + 100788;                //   100,004
    int*      deg     = wsi + 200792;                //   100,000
    int*      srow    = wsi + 300792;                // 1,301,248 (NBUCK*BCAP)
    unsigned* h0b     = (unsigned*)(wsi + 1602040);  // 3,200,000
    int*      pedge   = wsi + 1602040;               // aliases h0b: dead before gemm L1
    float*    agg1    = (float*)(wsi + 4802040);     // 6,400,000
    unsigned* h2b     = h0b;
    unsigned* wtgA    = (unsigned*)(wsi + 11202040); //     8,192
    unsigned* wtgB    = wtgA + 8192;                 //     2,560
    unsigned short* h2s = (unsigned short*)(wsi + 11212792); // 2,000,000 dw
    const size_t WS_C = 11212792ull * 4ull;          // 44.85 MB
    const size_t WS_B = 13212792ull * 4ull;          // 52.85 MB (fused path)

    const bool have_wt = (ws_size >= WS_C);
    unsigned* wtgA_arg = have_wt ? wtgA : nullptr;
    unsigned* wtgB_arg = have_wt ? wtgB : nullptr;

    // ---- graph prep: 2 dispatches + tiny memset (R10-verified padded-bucket scheme) ----
    hipMemsetAsync(gcursor, 0, 788 * sizeof(int), stream);
    bucket_scatter_wconv_kernel<<<NCOUNT + 43, 256, 0, stream>>>(
        rows, cols, gcursor, pedge, N_EDGES,
        w1_init, w1_root, w2_init, w2_root, wtgA_arg, wtgB_arg);
    bucket_sort_kernel<<<NBUCK, 256, 0, stream>>>(gcursor, pedge, srow, offsets, deg);

    const int NTILES = cdiv(N_NODES, 64);  // 1563

    if (ws_size >= WS_B) {
        gemm_fat_kernel<IN_CH, HID_CH, HID_CH><<<NTILES, 256, 0, stream>>>(
            x, (const unsigned short*)wtgA, b1, deg, (unsigned short*)h0b, agg1, N_NODES);
        pull_gemm_fused_kernel<<<cdiv(N_NODES, 16), 256, 0, stream>>>(
            offsets, deg, srow, h0b, agg1, (const unsigned short*)wtgB, b2,
            h2s, out, N_NODES);
        pull_bf16_kernel<N_CLS><<<cdiv(N_NODES * (N_CLS / 4), 256), 256, 0, stream>>>(
            offsets, deg, srow, (const unsigned*)h2s, out, N_NODES);
    } else if (have_wt) {
        gemm_fat_kernel<IN_CH, HID_CH, HID_CH><<<NTILES, 256, 0, stream>>>(
            x, (const unsigned short*)wtgA, b1, deg, (unsigned short*)h0b, agg1, N_NODES);
        pull_bf16_kernel<HID_CH><<<cdiv(N_NODES * (HID_CH / 4), 256), 256, 0, stream>>>(
            offsets, deg, srow, h0b, agg1, N_NODES);
        gemm_fat_kernel<HID_CH, N_CLS, N_CLS><<<NTILES, 256, 0, stream>>>(
            agg1, (const unsigned short*)wtgB, b2, deg, (unsigned short*)h2b, out, N_NODES);
        pull_bf16_kernel<N_CLS><<<cdiv(N_NODES * (N_CLS / 4), 256), 256, 0, stream>>>(
            offsets, deg, srow, h2b, out, N_NODES);
    } else {
        gemm_mfma_fused_kernel<IN_CH, HID_CH, HID_CH><<<NTILES, 256, 0, stream>>>(
            x, w1_init, w1_root, b1, deg, (unsigned short*)h0b, agg1, N_NODES);
        pull_bf16_kernel<HID_CH><<<cdiv(N_NODES * (HID_CH / 4), 256), 256, 0, stream>>>(
            offsets, deg, srow, h0b, agg1, N_NODES);
        gemm_mfma_fused_kernel<HID_CH, N_CLS, N_CLS><<<NTILES, 256, 0, stream>>>(
            agg1, w2_init, w2_root, b2, deg, (unsigned short*)h2b, out, N_NODES);
        pull_bf16_kernel<N_CLS><<<cdiv(N_NODES * (N_CLS / 4), 256), 256, 0, stream>>>(
            offsets, deg, srow, h2b, out, N_NODES);
    }
}